// Round 1
// baseline (1610.433 us; speedup 1.0000x reference)
//
#include <hip/hip_runtime.h>

#define HN 8
#define DH 256
#define HID 2048
#define BB 4
#define SS 2048
#define TT (BB*SS)
#define NQKV 2560      // (H + 2*KV) * D
#define NSLOTS 16384

typedef unsigned short u16;
typedef unsigned int u32;
typedef __bf16 bf16x8 __attribute__((ext_vector_type(8)));
typedef float f32x4 __attribute__((ext_vector_type(4)));
typedef u16 u16x4 __attribute__((ext_vector_type(4)));
typedef u16 u16x8 __attribute__((ext_vector_type(8)));

__device__ __forceinline__ u16 f2bf(float f) {
    u32 u = __builtin_bit_cast(u32, f);
    u = u + 0x7fffu + ((u >> 16) & 1u);   // RNE; inputs are never NaN
    return (u16)(u >> 16);
}
__device__ __forceinline__ float bf2f(u16 h) {
    u32 u = ((u32)h) << 16;
    return __builtin_bit_cast(float, u);
}
__device__ __forceinline__ void gload_lds16(const void* g, void* l) {
    __builtin_amdgcn_global_load_lds((__attribute__((address_space(1))) void*)g,
                                     (__attribute__((address_space(3))) void*)l,
                                     16, 0, 0);
}

// ---------------- fp32 -> bf16 conversion ----------------
__global__ __launch_bounds__(256) void cvt_f32_bf16(const float* __restrict__ in,
                                                    u16* __restrict__ out, long n) {
    long i = ((long)blockIdx.x * blockDim.x + threadIdx.x) * 4;
    long stride = (long)gridDim.x * blockDim.x * 4;
    for (; i < n; i += stride) {
        float4 v = *(const float4*)(in + i);
        u16x4 o4;
        o4[0] = f2bf(v.x); o4[1] = f2bf(v.y); o4[2] = f2bf(v.z); o4[3] = f2bf(v.w);
        *(u16x4*)(out + i) = o4;
    }
}

// ---------------- NT GEMM: C[M,N] = A[M,K] * B[N,K]^T  (m97 recipe) ----------------
// 128x128 tile, BK=32, 256 threads = 4 waves in 2x2, each wave 64x64 via 4x4 MFMA frags.
template<int OUTBF>
__global__ __launch_bounds__(256) void gemm_nt(const u16* __restrict__ A, const u16* __restrict__ B,
                                               void* __restrict__ C, int M, int N, int K) {
    __shared__ u16 As[128 * 32];
    __shared__ u16 Bs[128 * 32];
    const int tid = threadIdx.x;
    const int lane = tid & 63, w = tid >> 6;
    const int quad = lane >> 4, m16 = lane & 15;
    const int wm = w & 1, wn = w >> 1;
    const int r4 = tid >> 2, c8 = (tid & 3) * 8;
    const long arow = (long)blockIdx.x * 128;
    const long brow = (long)blockIdx.y * 128;

    f32x4 acc[4][4];
#pragma unroll
    for (int i = 0; i < 4; i++)
#pragma unroll
        for (int j = 0; j < 4; j++) acc[i][j] = (f32x4){0.f, 0.f, 0.f, 0.f};

    const u16* Ag = A + (arow + r4) * (long)K + c8;
    const u16* Bg = B + (brow + r4) * (long)K + c8;

    for (int k0 = 0; k0 < K; k0 += 32) {
        __syncthreads();
        gload_lds16(Ag + k0,                 (char*)As + tid * 16);
        gload_lds16(Ag + 64l * K + k0,       (char*)As + 4096 + tid * 16);
        gload_lds16(Bg + k0,                 (char*)Bs + tid * 16);
        gload_lds16(Bg + 64l * K + k0,       (char*)Bs + 4096 + tid * 16);
        __syncthreads();
        bf16x8 af[4], bfr[4];
#pragma unroll
        for (int mi = 0; mi < 4; mi++)
            af[mi] = *(const bf16x8*)(As + (wm * 64 + mi * 16 + m16) * 32 + quad * 8);
#pragma unroll
        for (int ni = 0; ni < 4; ni++)
            bfr[ni] = *(const bf16x8*)(Bs + (wn * 64 + ni * 16 + m16) * 32 + quad * 8);
#pragma unroll
        for (int mi = 0; mi < 4; mi++)
#pragma unroll
            for (int ni = 0; ni < 4; ni++)
                acc[mi][ni] = __builtin_amdgcn_mfma_f32_16x16x32_bf16(af[mi], bfr[ni], acc[mi][ni], 0, 0, 0);
    }
    // C/D layout: col = lane&15, row = quad*4 + reg  (m89/m91 verified)
#pragma unroll
    for (int mi = 0; mi < 4; mi++) {
#pragma unroll
        for (int ni = 0; ni < 4; ni++) {
            long col = brow + wn * 64 + ni * 16 + m16;
#pragma unroll
            for (int r = 0; r < 4; r++) {
                long row = arow + wm * 64 + mi * 16 + quad * 4 + r;
                float v = acc[mi][ni][r];
                if (OUTBF) ((u16*)C)[row * N + col] = f2bf(v);
                else       ((float*)C)[row * N + col] = v;
            }
        }
    }
}

// ---------------- RoPE + cache scatter ----------------
// q (8 heads) roped in-place in qkv (bf16), pre-scaled by 1/16 (exact).
// k roped -> kb (bf16) and key cache (fp32); v -> vb (bf16) and value cache (fp32).
__global__ __launch_bounds__(256) void rope_scatter(u16* __restrict__ qkv, const float* __restrict__ cosb,
        const float* __restrict__ sinb, const int* __restrict__ slots,
        u16* __restrict__ kb, u16* __restrict__ vb,
        float* __restrict__ kc, float* __restrict__ vc) {
    const int t = blockIdx.x, tid = threadIdx.x;
    const long qbase = (long)t * NQKV;
#pragma unroll
    for (int i = 0; i < 4; i++) {
        int idx = tid + i * 256;            // 0..1023 : 8 heads x 128 pairs
        int head = idx >> 7, d = idx & 127;
        long off = qbase + head * DH + d;
        float q1 = bf2f(qkv[off]), q2 = bf2f(qkv[off + 128]);
        float c = cosb[(long)t * 128 + d], s = sinb[(long)t * 128 + d];
        qkv[off]       = f2bf((q1 * c - q2 * s) * 0.0625f);
        qkv[off + 128] = f2bf((q2 * c + q1 * s) * 0.0625f);
    }
    const int slot = slots[t];
    if (tid < 128) {
        int d = tid;
        long off = qbase + HN * DH + d;
        float k1 = bf2f(qkv[off]), k2 = bf2f(qkv[off + 128]);
        float c = cosb[(long)t * 128 + d], s = sinb[(long)t * 128 + d];
        float kn1 = k1 * c - k2 * s, kn2 = k2 * c + k1 * s;
        kb[(long)t * DH + d]       = f2bf(kn1);
        kb[(long)t * DH + d + 128] = f2bf(kn2);
        kc[(long)slot * DH + d]       = kn1;
        kc[(long)slot * DH + d + 128] = kn2;
    }
    {
        int d = tid;
        u16 vraw = qkv[qbase + (HN + 1) * DH + d];
        vb[(long)t * DH + d] = vraw;
        vc[(long)slot * DH + d] = bf2f(vraw);
    }
}

// ---------------- Flash attention (causal, GQA KV=1) ----------------
// Block = (b, h, 64 q rows); 4 waves x 16 q rows. kv-tile = 32.
// Q A-frags in registers; K staged via global_load_lds into [kstep][kv][32] panels;
// V transposed into LDS (stride 40); P via LDS round-trip (m120 layout transform).
__global__ __launch_bounds__(256) void flash_attn(const u16* __restrict__ qkv, const u16* __restrict__ kb,
                                                  const u16* __restrict__ vb, u16* __restrict__ attn) {
    __shared__ u16 Ks[8 * 32 * 32];   // 16 KB : [ks 8][kv 32][d32 32]
    __shared__ u16 Vt[256 * 40];      // 20 KB : [d 256][kv 32 pad40]
    __shared__ u16 Pl[4 * 16 * 40];   // 5 KB  : per-wave [row 16][kv 32 pad40]
    const int tid = threadIdx.x;
    const int lane = tid & 63, w = tid >> 6;
    const int quad = lane >> 4, m16 = lane & 15;
    const int qb = blockIdx.x, h = blockIdx.y, b = blockIdx.z;
    const int qrow_w = qb * 64 + w * 16;

    bf16x8 aq[8];   // A-operand: A[m=lane&15][k=quad*8+j], 8 ksteps cover D=256
    {
        const u16* qp = qkv + (long)(b * SS + qrow_w + m16) * NQKV + h * DH;
#pragma unroll
        for (int ks = 0; ks < 8; ks++)
            aq[ks] = *(const bf16x8*)(qp + ks * 32 + quad * 8);
    }
    f32x4 o[16];
#pragma unroll
    for (int i = 0; i < 16; i++) o[i] = (f32x4){0.f, 0.f, 0.f, 0.f};
    float m_run[4] = {-1e30f, -1e30f, -1e30f, -1e30f};
    float l_run[4] = {0.f, 0.f, 0.f, 0.f};
    const long kvrow0 = (long)b * SS;
    const int ntiles = 2 * qb + 2;

    for (int it = 0; it < ntiles; it++) {
        const int kv0 = it * 32;
        __syncthreads();   // protect Ks/Vt/Pl overwrite vs previous-iter reads
        // stage K: 1024 16B chunks, panel layout; chunk j -> ks=j>>7, kv=(j>>2)&31, dc=j&3
#pragma unroll
        for (int c = 0; c < 4; c++) {
            int j = c * 256 + tid;
            int ks = j >> 7, kv = (j >> 2) & 31, dc = j & 3;
            gload_lds16(kb + (kvrow0 + kv0 + kv) * DH + ks * 32 + dc * 8, (char*)Ks + j * 16);
        }
        // stage V transposed
#pragma unroll
        for (int c = 0; c < 4; c++) {
            int kvr = c * 8 + (tid >> 5), d8 = tid & 31;
            u16x8 vv = *(const u16x8*)(vb + (kvrow0 + kv0 + kvr) * DH + d8 * 8);
#pragma unroll
            for (int e = 0; e < 8; e++)
                Vt[(d8 * 8 + e) * 40 + kvr] = vv[e];
        }
        __syncthreads();   // staging visible (vmcnt+lgkmcnt drained by barrier)

        // Q K^T : scores 16x32 per wave (pre-scaled by 1/16 via q)
        f32x4 sc[2];
        sc[0] = (f32x4){0.f, 0.f, 0.f, 0.f};
        sc[1] = (f32x4){0.f, 0.f, 0.f, 0.f};
#pragma unroll
        for (int ks = 0; ks < 8; ks++)
#pragma unroll
            for (int n = 0; n < 2; n++) {
                bf16x8 kf = *(const bf16x8*)(Ks + ks * 1024 + (n * 16 + m16) * 32 + quad * 8);
                sc[n] = __builtin_amdgcn_mfma_f32_16x16x32_bf16(aq[ks], kf, sc[n], 0, 0, 0);
            }
        // causal mask (only tiles overlapping the q range)
        if (it >= 2 * qb) {
            const int qg = qrow_w + quad * 4;
#pragma unroll
            for (int n = 0; n < 2; n++) {
                int kvg = kv0 + n * 16 + m16;
#pragma unroll
                for (int r = 0; r < 4; r++)
                    if (kvg > qg + r) sc[n][r] = -1e30f;
            }
        }
        // online softmax: rows live in 16-lane groups (row = quad*4+reg)
        float mx[4], alpha[4], rsum[4];
#pragma unroll
        for (int r = 0; r < 4; r++) mx[r] = fmaxf(sc[0][r], sc[1][r]);
#pragma unroll
        for (int off = 1; off <= 8; off <<= 1)
#pragma unroll
            for (int r = 0; r < 4; r++) mx[r] = fmaxf(mx[r], __shfl_xor(mx[r], off));
#pragma unroll
        for (int r = 0; r < 4; r++) {
            float mn = fmaxf(m_run[r], mx[r]);
            alpha[r] = __expf(m_run[r] - mn);
            m_run[r] = mn;
            rsum[r] = 0.f;
        }
#pragma unroll
        for (int n = 0; n < 2; n++)
#pragma unroll
            for (int r = 0; r < 4; r++) {
                float p = __expf(sc[n][r] - m_run[r]);
                sc[n][r] = p;
                rsum[r] += p;
            }
#pragma unroll
        for (int off = 1; off <= 8; off <<= 1)
#pragma unroll
            for (int r = 0; r < 4; r++) rsum[r] += __shfl_xor(rsum[r], off);
#pragma unroll
        for (int r = 0; r < 4; r++) l_run[r] = l_run[r] * alpha[r] + rsum[r];
#pragma unroll
        for (int nf = 0; nf < 16; nf++)
#pragma unroll
            for (int r = 0; r < 4; r++) o[nf][r] *= alpha[r];
        // P: C-layout -> LDS -> A-layout
#pragma unroll
        for (int n = 0; n < 2; n++)
#pragma unroll
            for (int r = 0; r < 4; r++)
                Pl[w * 640 + (quad * 4 + r) * 40 + n * 16 + m16] = f2bf(sc[n][r]);
        __syncthreads();   // Pl visible (and Ks reads complete before restage)
        // P V : O[16 x 256] accumulate, K-dim = 32 kv (one MFMA step)
        bf16x8 ap = *(const bf16x8*)(Pl + w * 640 + m16 * 40 + quad * 8);
#pragma unroll
        for (int nf = 0; nf < 16; nf++) {
            bf16x8 vf = *(const bf16x8*)(Vt + (nf * 16 + m16) * 40 + quad * 8);
            o[nf] = __builtin_amdgcn_mfma_f32_16x16x32_bf16(ap, vf, o[nf], 0, 0, 0);
        }
    }
    float inv[4];
#pragma unroll
    for (int r = 0; r < 4; r++) inv[r] = 1.f / l_run[r];
#pragma unroll
    for (int nf = 0; nf < 16; nf++)
#pragma unroll
        for (int r = 0; r < 4; r++) {
            long row = (long)(b * SS + qrow_w + quad * 4 + r);
            attn[row * (HN * DH) + h * DH + nf * 16 + m16] = f2bf(o[nf][r] * inv[r]);
        }
}

// ---------------- launch ----------------
extern "C" void kernel_launch(void* const* d_in, const int* in_sizes, int n_in,
                              void* d_out, int out_size, void* d_ws, size_t ws_size,
                              hipStream_t stream) {
    (void)in_sizes; (void)n_in; (void)out_size; (void)ws_size;
    const float* hidden = (const float*)d_in[0];
    const float* cosb   = (const float*)d_in[1];
    const float* sinb   = (const float*)d_in[2];
    const int*   slots  = (const int*)d_in[3];
    const float* kc_in  = (const float*)d_in[4];
    const float* vc_in  = (const float*)d_in[5];
    const float* w_qkv  = (const float*)d_in[6];
    const float* w_o    = (const float*)d_in[7];

    float* out    = (float*)d_out;
    float* kc_out = out + (size_t)TT * HID;            // 16,777,216
    float* vc_out = kc_out + (size_t)NSLOTS * DH;      // +4,194,304

    char* p = (char*)d_ws;
    u16* hid_b  = (u16*)p;  p += (size_t)TT * HID * 2;     // 33.6 MB (aliased by attn_b later)
    u16* wqkv_b = (u16*)p;  p += (size_t)NQKV * HID * 2;   // 10.5 MB
    u16* wo_b   = (u16*)p;  p += (size_t)HID * HID * 2;    // 8.4 MB
    u16* kb     = (u16*)p;  p += (size_t)TT * DH * 2;      // 4.2 MB
    u16* vb     = (u16*)p;  p += (size_t)TT * DH * 2;      // 4.2 MB
    u16* attn_b = hid_b;                 // hid_b dead after GEMM1; safe alias
    u16* qkv_b  = (u16*)d_out;           // out region (67 MB) as scratch; dead before GEMM2 writes

    // caches: full copy then scatter-overwrite (correct for arbitrary slots)
    hipMemcpyAsync(kc_out, kc_in, (size_t)NSLOTS * DH * 4, hipMemcpyDeviceToDevice, stream);
    hipMemcpyAsync(vc_out, vc_in, (size_t)NSLOTS * DH * 4, hipMemcpyDeviceToDevice, stream);

    cvt_f32_bf16<<<dim3(2048), dim3(256), 0, stream>>>(hidden, hid_b, (long)TT * HID);
    cvt_f32_bf16<<<dim3(640),  dim3(256), 0, stream>>>(w_qkv, wqkv_b, (long)NQKV * HID);
    cvt_f32_bf16<<<dim3(512),  dim3(256), 0, stream>>>(w_o,   wo_b,   (long)HID * HID);

    gemm_nt<1><<<dim3(TT / 128, NQKV / 128), dim3(256), 0, stream>>>(hid_b, wqkv_b, qkv_b, TT, NQKV, HID);
    rope_scatter<<<dim3(TT), dim3(256), 0, stream>>>(qkv_b, cosb, sinb, slots, kb, vb, kc_out, vc_out);
    flash_attn<<<dim3(SS / 64, HN, BB), dim3(256), 0, stream>>>(qkv_b, kb, vb, attn_b);
    gemm_nt<0><<<dim3(TT / 128, HID / 128), dim3(256), 0, stream>>>(attn_b, wo_b, out, TT, HID, HID);
}

// Round 2
// 818.541 us; speedup vs baseline: 1.9674x; 1.9674x over previous
//
#include <hip/hip_runtime.h>

#define HN 8
#define DH 256
#define HID 2048
#define BB 4
#define SS 2048
#define TT (BB*SS)
#define NQKV 2560      // (H + 2*KV) * D
#define NSLOTS 16384

typedef unsigned short u16;
typedef unsigned int u32;
typedef __bf16 bf16x8 __attribute__((ext_vector_type(8)));
typedef float f32x4 __attribute__((ext_vector_type(4)));
typedef u16 u16x4 __attribute__((ext_vector_type(4)));
typedef u16 u16x8 __attribute__((ext_vector_type(8)));

__device__ __forceinline__ u16 f2bf(float f) {
    u32 u = __builtin_bit_cast(u32, f);
    u = u + 0x7fffu + ((u >> 16) & 1u);   // RNE; inputs are never NaN
    return (u16)(u >> 16);
}
__device__ __forceinline__ float bf2f(u16 h) {
    u32 u = ((u32)h) << 16;
    return __builtin_bit_cast(float, u);
}
__device__ __forceinline__ void gload_lds16(const void* g, void* l) {
    __builtin_amdgcn_global_load_lds((__attribute__((address_space(1))) void*)g,
                                     (__attribute__((address_space(3))) void*)l,
                                     16, 0, 0);
}

// ---------------- fp32 -> bf16 conversion ----------------
__global__ __launch_bounds__(256) void cvt_f32_bf16(const float* __restrict__ in,
                                                    u16* __restrict__ out, long n) {
    long i = ((long)blockIdx.x * blockDim.x + threadIdx.x) * 4;
    long stride = (long)gridDim.x * blockDim.x * 4;
    for (; i < n; i += stride) {
        float4 v = *(const float4*)(in + i);
        u16x4 o4;
        o4[0] = f2bf(v.x); o4[1] = f2bf(v.y); o4[2] = f2bf(v.z); o4[3] = f2bf(v.w);
        *(u16x4*)(out + i) = o4;
    }
}

// ---------------- NT GEMM: C[M,N] = A[M,K] * B[N,K]^T  (m97 recipe) ----------------
template<int OUTBF>
__global__ __launch_bounds__(256) void gemm_nt(const u16* __restrict__ A, const u16* __restrict__ B,
                                               void* __restrict__ C, int M, int N, int K) {
    __shared__ u16 As[128 * 32];
    __shared__ u16 Bs[128 * 32];
    const int tid = threadIdx.x;
    const int lane = tid & 63, w = tid >> 6;
    const int quad = lane >> 4, m16 = lane & 15;
    const int wm = w & 1, wn = w >> 1;
    const int r4 = tid >> 2, c8 = (tid & 3) * 8;
    const long arow = (long)blockIdx.x * 128;
    const long brow = (long)blockIdx.y * 128;

    f32x4 acc[4][4];
#pragma unroll
    for (int i = 0; i < 4; i++)
#pragma unroll
        for (int j = 0; j < 4; j++) acc[i][j] = (f32x4){0.f, 0.f, 0.f, 0.f};

    const u16* Ag = A + (arow + r4) * (long)K + c8;
    const u16* Bg = B + (brow + r4) * (long)K + c8;

    for (int k0 = 0; k0 < K; k0 += 32) {
        __syncthreads();
        gload_lds16(Ag + k0,                 (char*)As + tid * 16);
        gload_lds16(Ag + 64l * K + k0,       (char*)As + 4096 + tid * 16);
        gload_lds16(Bg + k0,                 (char*)Bs + tid * 16);
        gload_lds16(Bg + 64l * K + k0,       (char*)Bs + 4096 + tid * 16);
        __syncthreads();
        bf16x8 af[4], bfr[4];
#pragma unroll
        for (int mi = 0; mi < 4; mi++)
            af[mi] = *(const bf16x8*)(As + (wm * 64 + mi * 16 + m16) * 32 + quad * 8);
#pragma unroll
        for (int ni = 0; ni < 4; ni++)
            bfr[ni] = *(const bf16x8*)(Bs + (wn * 64 + ni * 16 + m16) * 32 + quad * 8);
#pragma unroll
        for (int mi = 0; mi < 4; mi++)
#pragma unroll
            for (int ni = 0; ni < 4; ni++)
                acc[mi][ni] = __builtin_amdgcn_mfma_f32_16x16x32_bf16(af[mi], bfr[ni], acc[mi][ni], 0, 0, 0);
    }
#pragma unroll
    for (int mi = 0; mi < 4; mi++) {
#pragma unroll
        for (int ni = 0; ni < 4; ni++) {
            long col = brow + wn * 64 + ni * 16 + m16;
#pragma unroll
            for (int r = 0; r < 4; r++) {
                long row = arow + wm * 64 + mi * 16 + quad * 4 + r;
                float v = acc[mi][ni][r];
                if (OUTBF) ((u16*)C)[row * N + col] = f2bf(v);
                else       ((float*)C)[row * N + col] = v;
            }
        }
    }
}

// ---------------- RoPE + cache scatter ----------------
// q roped in-place in qkv (bf16), pre-scaled by 1/16; k roped -> kb (bf16) + key cache (fp32);
// v -> value cache (fp32). (v for flash comes from transpose_v.)
__global__ __launch_bounds__(256) void rope_scatter(u16* __restrict__ qkv, const float* __restrict__ cosb,
        const float* __restrict__ sinb, const int* __restrict__ slots,
        u16* __restrict__ kb, float* __restrict__ kc, float* __restrict__ vc) {
    const int t = blockIdx.x, tid = threadIdx.x;
    const long qbase = (long)t * NQKV;
#pragma unroll
    for (int i = 0; i < 4; i++) {
        int idx = tid + i * 256;            // 0..1023 : 8 heads x 128 pairs
        int head = idx >> 7, d = idx & 127;
        long off = qbase + head * DH + d;
        float q1 = bf2f(qkv[off]), q2 = bf2f(qkv[off + 128]);
        float c = cosb[(long)t * 128 + d], s = sinb[(long)t * 128 + d];
        qkv[off]       = f2bf((q1 * c - q2 * s) * 0.0625f);
        qkv[off + 128] = f2bf((q2 * c + q1 * s) * 0.0625f);
    }
    const int slot = slots[t];
    if (tid < 128) {
        int d = tid;
        long off = qbase + HN * DH + d;
        float k1 = bf2f(qkv[off]), k2 = bf2f(qkv[off + 128]);
        float c = cosb[(long)t * 128 + d], s = sinb[(long)t * 128 + d];
        float kn1 = k1 * c - k2 * s, kn2 = k2 * c + k1 * s;
        kb[(long)t * DH + d]       = f2bf(kn1);
        kb[(long)t * DH + d + 128] = f2bf(kn2);
        kc[(long)slot * DH + d]       = kn1;
        kc[(long)slot * DH + d + 128] = kn2;
    }
    {
        int d = tid;
        vc[(long)slot * DH + d] = bf2f(qkv[qbase + (HN + 1) * DH + d]);
    }
}

// ---------------- V transpose: qkv v-slice -> vbt[b][d][s] ----------------
__global__ __launch_bounds__(256) void transpose_v(const u16* __restrict__ qkv, u16* __restrict__ vbt) {
    const int tid = threadIdx.x;
    const int s0 = blockIdx.x * 64, d0 = blockIdx.y * 64, b = blockIdx.z;
#pragma unroll
    for (int i = 0; i < 2; i++) {
        int d = d0 + i * 32 + (tid >> 3);
        int s = s0 + (tid & 7) * 8;
        u16x8 v;
#pragma unroll
        for (int e = 0; e < 8; e++)
            v[e] = qkv[(long)(b * SS + s + e) * NQKV + (HN + 1) * DH + d];
        *(u16x8*)(vbt + ((long)b * DH + d) * SS + s) = v;
    }
}

// ---------------- Flash attention (causal, GQA KV=1) ----------------
// Block = (b, h, 64 q rows), LPT order (qb descending). 4 waves x 16 q rows, kv-tile 32.
// Ks [32 kv][264] padded; Vt [256 d][40] padded (from pre-transposed vbt);
// register prefetch of next tile's K/V hides global latency; Pl round-trip is wave-private.
__global__ __launch_bounds__(256, 3) void flash_attn(const u16* __restrict__ qkv, const u16* __restrict__ kb,
                                                     const u16* __restrict__ vbt, u16* __restrict__ attn) {
    __shared__ u16 Ks[32 * 264];      // 16.5 KB
    __shared__ u16 Vt[256 * 40];      // 20 KB
    __shared__ u16 Pl[4 * 16 * 40];   // 5 KB
    const int tid = threadIdx.x;
    const int lane = tid & 63, w = tid >> 6;
    const int quad = lane >> 4, m16 = lane & 15;
    const int qb = (int)gridDim.x - 1 - (int)blockIdx.x;   // LPT: longest blocks first
    const int h = blockIdx.y, b = blockIdx.z;
    const int qrow_w = qb * 64 + w * 16;

    // staging index decomposition (per thread, 4 chunks each for K and V)
    const int k_kv = tid >> 5, k_c = tid & 31;             // + i*8 rows
    const int v_d = tid >> 2, v_c = tid & 3;               // + i*64 rows

    bf16x8 aq[8];
    {
        const u16* qp = qkv + (long)(b * SS + qrow_w + m16) * NQKV + h * DH;
#pragma unroll
        for (int ks = 0; ks < 8; ks++)
            aq[ks] = *(const bf16x8*)(qp + ks * 32 + quad * 8);
    }
    f32x4 o[16];
#pragma unroll
    for (int i = 0; i < 16; i++) o[i] = (f32x4){0.f, 0.f, 0.f, 0.f};
    float m_run[4] = {-1e30f, -1e30f, -1e30f, -1e30f};
    float l_run[4] = {0.f, 0.f, 0.f, 0.f};
    const long kvrow0 = (long)b * SS;
    const u16* vbase = vbt + (long)b * DH * SS;
    const int ntiles = 2 * qb + 2;

    // prologue: prefetch tile 0 into registers
    u16x8 kreg[4], vreg[4];
#pragma unroll
    for (int i = 0; i < 4; i++) {
        kreg[i] = *(const u16x8*)(kb + (kvrow0 + k_kv + i * 8) * DH + k_c * 8);
        vreg[i] = *(const u16x8*)(vbase + (long)(v_d) * SS + 0 + v_c * 8 + (long)i * 64 * SS);
    }

    for (int it = 0; it < ntiles; it++) {
        const int kv0 = it * 32;
        __syncthreads();   // all waves done reading previous tile's LDS
#pragma unroll
        for (int i = 0; i < 4; i++) {
            *(u16x8*)(Ks + (k_kv + i * 8) * 264 + k_c * 8) = kreg[i];
            *(u16x8*)(Vt + (v_d + i * 64) * 40 + v_c * 8) = vreg[i];
        }
        __syncthreads();   // staging visible
        // prefetch next tile while computing this one
        if (it + 1 < ntiles) {
            const int kv1 = kv0 + 32;
#pragma unroll
            for (int i = 0; i < 4; i++) {
                kreg[i] = *(const u16x8*)(kb + (kvrow0 + kv1 + k_kv + i * 8) * DH + k_c * 8);
                vreg[i] = *(const u16x8*)(vbase + ((long)(v_d + i * 64)) * SS + kv1 + v_c * 8);
            }
        }

        // Q K^T : scores 16x32 per wave (q pre-scaled by 1/16)
        f32x4 sc[2];
        sc[0] = (f32x4){0.f, 0.f, 0.f, 0.f};
        sc[1] = (f32x4){0.f, 0.f, 0.f, 0.f};
#pragma unroll
        for (int ks = 0; ks < 8; ks++)
#pragma unroll
            for (int n = 0; n < 2; n++) {
                bf16x8 kf = *(const bf16x8*)(Ks + (n * 16 + m16) * 264 + ks * 32 + quad * 8);
                sc[n] = __builtin_amdgcn_mfma_f32_16x16x32_bf16(aq[ks], kf, sc[n], 0, 0, 0);
            }
        // causal mask (only tiles overlapping the q range)
        if (it >= 2 * qb) {
            const int qg = qrow_w + quad * 4;
#pragma unroll
            for (int n = 0; n < 2; n++) {
                int kvg = kv0 + n * 16 + m16;
#pragma unroll
                for (int r = 0; r < 4; r++)
                    if (kvg > qg + r) sc[n][r] = -1e30f;
            }
        }
        // online softmax (rows live in 16-lane groups; row = quad*4+reg)
        float mx[4], alpha[4], rsum[4];
#pragma unroll
        for (int r = 0; r < 4; r++) mx[r] = fmaxf(sc[0][r], sc[1][r]);
#pragma unroll
        for (int off = 1; off <= 8; off <<= 1)
#pragma unroll
            for (int r = 0; r < 4; r++) mx[r] = fmaxf(mx[r], __shfl_xor(mx[r], off));
#pragma unroll
        for (int r = 0; r < 4; r++) {
            float mn = fmaxf(m_run[r], mx[r]);
            alpha[r] = __expf(m_run[r] - mn);
            m_run[r] = mn;
            rsum[r] = 0.f;
        }
#pragma unroll
        for (int n = 0; n < 2; n++)
#pragma unroll
            for (int r = 0; r < 4; r++) {
                float p = __expf(sc[n][r] - m_run[r]);
                sc[n][r] = p;
                rsum[r] += p;
            }
#pragma unroll
        for (int off = 1; off <= 8; off <<= 1)
#pragma unroll
            for (int r = 0; r < 4; r++) rsum[r] += __shfl_xor(rsum[r], off);
#pragma unroll
        for (int r = 0; r < 4; r++) l_run[r] = l_run[r] * alpha[r] + rsum[r];
#pragma unroll
        for (int nf = 0; nf < 16; nf++)
#pragma unroll
            for (int r = 0; r < 4; r++) o[nf][r] *= alpha[r];
        // P: C-layout -> wave-private LDS -> A-layout (no block barrier needed)
#pragma unroll
        for (int n = 0; n < 2; n++)
#pragma unroll
            for (int r = 0; r < 4; r++)
                Pl[w * 640 + (quad * 4 + r) * 40 + n * 16 + m16] = f2bf(sc[n][r]);
        __builtin_amdgcn_s_waitcnt(0);   // drain lgkm for wave-private Pl round-trip
        bf16x8 ap = *(const bf16x8*)(Pl + w * 640 + m16 * 40 + quad * 8);
#pragma unroll
        for (int nf = 0; nf < 16; nf++) {
            bf16x8 vf = *(const bf16x8*)(Vt + (nf * 16 + m16) * 40 + quad * 8);
            o[nf] = __builtin_amdgcn_mfma_f32_16x16x32_bf16(ap, vf, o[nf], 0, 0, 0);
        }
    }
    float inv[4];
#pragma unroll
    for (int r = 0; r < 4; r++) inv[r] = 1.f / l_run[r];
#pragma unroll
    for (int nf = 0; nf < 16; nf++)
#pragma unroll
        for (int r = 0; r < 4; r++) {
            long row = (long)(b * SS + qrow_w + quad * 4 + r);
            attn[row * (HN * DH) + h * DH + nf * 16 + m16] = f2bf(o[nf][r] * inv[r]);
        }
}

// ---------------- launch ----------------
extern "C" void kernel_launch(void* const* d_in, const int* in_sizes, int n_in,
                              void* d_out, int out_size, void* d_ws, size_t ws_size,
                              hipStream_t stream) {
    (void)in_sizes; (void)n_in; (void)out_size; (void)ws_size;
    const float* hidden = (const float*)d_in[0];
    const float* cosb   = (const float*)d_in[1];
    const float* sinb   = (const float*)d_in[2];
    const int*   slots  = (const int*)d_in[3];
    const float* kc_in  = (const float*)d_in[4];
    const float* vc_in  = (const float*)d_in[5];
    const float* w_qkv  = (const float*)d_in[6];
    const float* w_o    = (const float*)d_in[7];

    float* out    = (float*)d_out;
    float* kc_out = out + (size_t)TT * HID;
    float* vc_out = kc_out + (size_t)NSLOTS * DH;

    char* p = (char*)d_ws;
    u16* hid_b  = (u16*)p;  p += (size_t)TT * HID * 2;     // 33.6 MB
    u16* wqkv_b = (u16*)p;  p += (size_t)NQKV * HID * 2;   // 10.5 MB
    u16* wo_b   = (u16*)p;  p += (size_t)HID * HID * 2;    // 8.4 MB
    u16* kb     = (u16*)p;  p += (size_t)TT * DH * 2;      // 4.2 MB
    u16* vbt    = (u16*)p;  p += (size_t)TT * DH * 2;      // 4.2 MB  [b][d][s]
    u16* attn_b = hid_b;                 // hid_b dead after GEMM1
    u16* qkv_b  = (u16*)d_out;           // out region scratch; dead before GEMM2 writes

    hipMemcpyAsync(kc_out, kc_in, (size_t)NSLOTS * DH * 4, hipMemcpyDeviceToDevice, stream);
    hipMemcpyAsync(vc_out, vc_in, (size_t)NSLOTS * DH * 4, hipMemcpyDeviceToDevice, stream);

    cvt_f32_bf16<<<dim3(2048), dim3(256), 0, stream>>>(hidden, hid_b, (long)TT * HID);
    cvt_f32_bf16<<<dim3(640),  dim3(256), 0, stream>>>(w_qkv, wqkv_b, (long)NQKV * HID);
    cvt_f32_bf16<<<dim3(512),  dim3(256), 0, stream>>>(w_o,   wo_b,   (long)HID * HID);

    gemm_nt<1><<<dim3(TT / 128, NQKV / 128), dim3(256), 0, stream>>>(hid_b, wqkv_b, qkv_b, TT, NQKV, HID);
    rope_scatter<<<dim3(TT), dim3(256), 0, stream>>>(qkv_b, cosb, sinb, slots, kb, kc_out, vc_out);
    transpose_v<<<dim3(SS / 64, DH / 64, BB), dim3(256), 0, stream>>>(qkv_b, vbt);
    flash_attn<<<dim3(SS / 64, HN, BB), dim3(256), 0, stream>>>(qkv_b, kb, vbt, attn_b);
    gemm_nt<0><<<dim3(TT / 128, HID / 128), dim3(256), 0, stream>>>(attn_b, wo_b, out, TT, HID, HID);
}